// Round 4
// baseline (451.460 us; speedup 1.0000x reference)
//
#include <hip/hip_runtime.h>

#define B_ 8
#define CQ_ 256
#define CKV_ 512
#define N_ 4096
#define DQK_ 32

typedef __bf16 bf16;
typedef __bf16 bf16x4 __attribute__((ext_vector_type(4)));
typedef __bf16 bf16x8 __attribute__((ext_vector_type(8)));
typedef float f32x4 __attribute__((ext_vector_type(4)));

// ---------------- weight convert fp32 -> bf16 ----------------
__global__ void k_convert_w(const float* __restrict__ Wq, const float* __restrict__ Wk,
                            const float* __restrict__ Wv,
                            bf16* __restrict__ wq, bf16* __restrict__ wk, bf16* __restrict__ wv) {
    int i = blockIdx.x * 256 + threadIdx.x;
    if (i < 8192) wq[i] = (bf16)Wq[i];
    else if (i < 24576) wk[i - 8192] = (bf16)Wk[i - 8192];
    else if (i < 155648) wv[i - 24576] = (bf16)Wv[i - 24576];
}

// ---------------- bilinear resize 32x32 -> 64x64, transposed to [b][n][u] ----------------
__global__ __launch_bounds__(256) void k_resize(const float* __restrict__ kv, bf16* __restrict__ kvr) {
    const int yo = blockIdx.x;   // output row 0..63
    const int b  = blockIdx.y;
    const int tid = threadIdx.x;
    __shared__ float r0[64][33];
    __shared__ float r1[64][33];
    int ty = yo >> 1;
    int y0, y1; float wy0, wy1;
    if ((yo & 1) == 0) { y0 = ty > 0 ? ty - 1 : 0; y1 = ty; wy0 = 0.25f; wy1 = 0.75f; }
    else               { y0 = ty; y1 = ty < 31 ? ty + 1 : 31; wy0 = 0.75f; wy1 = 0.25f; }
    const int u_loc = tid & 63;
    const int xo_base = tid >> 6;
    for (int uc = 0; uc < CKV_; uc += 64) {
        __syncthreads();
        for (int i = 0; i < 8; ++i) {
            int idx = tid + i * 256;
            int u = idx >> 5, x = idx & 31;
            const float* src = kv + ((size_t)b * CKV_ + uc + u) * 1024 + x;
            r0[u][x] = src[y0 * 32];
            r1[u][x] = src[y1 * 32];
        }
        __syncthreads();
        for (int i = 0; i < 16; ++i) {
            int xo = xo_base + i * 4;
            int tx = xo >> 1;
            int xa, xb; float wxa, wxb;
            if ((xo & 1) == 0) { xa = tx > 0 ? tx - 1 : 0; xb = tx; wxa = 0.25f; wxb = 0.75f; }
            else               { xa = tx; xb = tx < 31 ? tx + 1 : 31; wxa = 0.75f; wxb = 0.25f; }
            float v0 = wxa * r0[u_loc][xa] + wxb * r0[u_loc][xb];
            float v1 = wxa * r1[u_loc][xa] + wxb * r1[u_loc][xb];
            float val = wy0 * v0 + wy1 * v1;
            kvr[((size_t)b * N_ + yo * 64 + xo) * CKV_ + uc + u_loc] = (bf16)val;
        }
    }
}

// ---------------- fused: transpose query tile to LDS + q projection ----------------
// Removes the 64MB qryT write + 64MB re-read of the old 2-kernel path.
__global__ __launch_bounds__(256) void k_proj_q_fused(const float* __restrict__ query,
                                                      const bf16* __restrict__ W,     // [32][256]
                                                      const float* __restrict__ bias, // [32]
                                                      bf16* __restrict__ qTb) {       // [B][N][32]
    __shared__ bf16 tile[64][264];   // [n][c], row stride 528B (16B-aligned)
    const int n0 = blockIdx.x * 64;
    const int b  = blockIdx.y;
    const int tid = threadIdx.x;
    const int xi = tid & 15, c0 = tid >> 4;
    for (int pass = 0; pass < 16; ++pass) {
        int c = c0 + pass * 16;
        const float4 v = *(const float4*)(query + ((size_t)b * CQ_ + c) * N_ + n0 + xi * 4);
        tile[xi * 4 + 0][c] = (bf16)v.x;
        tile[xi * 4 + 1][c] = (bf16)v.y;
        tile[xi * 4 + 2][c] = (bf16)v.z;
        tile[xi * 4 + 3][c] = (bf16)v.w;
    }
    __syncthreads();
    const int w = tid >> 6, lane = tid & 63;
    const int l16 = lane & 15, quad = lane >> 4;
    const int ct = w & 1, nh = w >> 1;
    f32x4 acc[2];
    acc[0] = (f32x4){0.f, 0.f, 0.f, 0.f}; acc[1] = (f32x4){0.f, 0.f, 0.f, 0.f};
    const bf16* aptr = W + (ct * 16 + l16) * CQ_ + quad * 8;
#pragma unroll
    for (int ks = 0; ks < 8; ++ks) {
        bf16x8 af = *(const bf16x8*)(aptr + ks * 32);
        for (int j = 0; j < 2; ++j) {
            bf16x8 bfv = *(const bf16x8*)&tile[nh * 32 + j * 16 + l16][ks * 32 + quad * 8];
            acc[j] = __builtin_amdgcn_mfma_f32_16x16x32_bf16(af, bfv, acc[j], 0, 0, 0);
        }
    }
    for (int j = 0; j < 2; ++j)
        for (int r = 0; r < 4; ++r) {
            int d = ct * 16 + quad * 4 + r;
            int n = n0 + nh * 32 + j * 16 + l16;
            qTb[((size_t)b * N_ + n) * DQK_ + d] = (bf16)(acc[j][r] + bias[d]);
        }
}

// ---------------- k projection: D[32 x m] = W[32x512] * kvr^T, store [b][m][32] ----------------
__global__ __launch_bounds__(256) void k_proj_k(const bf16* __restrict__ W,     // [32][512]
                                                const float* __restrict__ bias, // [32]
                                                const bf16* __restrict__ Bm,    // [B][N][512]
                                                bf16* __restrict__ outT) {      // [B][N][32]
    const int mb = blockIdx.x * 128;
    const int b  = blockIdx.y;
    const int tid = threadIdx.x;
    const int w = tid >> 6, lane = tid & 63;
    const int l16 = lane & 15, quad = lane >> 4;
    const int ct = w & 1;
    const int mhalf = (w >> 1) * 64;
    f32x4 acc[4];
    for (int j = 0; j < 4; ++j) acc[j] = (f32x4){0.f, 0.f, 0.f, 0.f};
    const bf16* aptr  = W + (ct * 16 + l16) * CKV_ + quad * 8;
    const bf16* bbase = Bm + ((size_t)b * N_ + mb + mhalf) * CKV_ + quad * 8;
#pragma unroll
    for (int ks = 0; ks < 16; ++ks) {
        bf16x8 af = *(const bf16x8*)(aptr + ks * 32);
        for (int j = 0; j < 4; ++j) {
            bf16x8 bfv = *(const bf16x8*)(bbase + (size_t)(j * 16 + l16) * CKV_ + ks * 32);
            acc[j] = __builtin_amdgcn_mfma_f32_16x16x32_bf16(af, bfv, acc[j], 0, 0, 0);
        }
    }
    for (int j = 0; j < 4; ++j)
        for (int r = 0; r < 4; ++r) {
            int d = ct * 16 + quad * 4 + r;
            int m = mb + mhalf + j * 16 + l16;
            outT[((size_t)b * N_ + m) * DQK_ + d] = (bf16)(acc[j][r] + bias[d]);
        }
}

// ---------------- v projection: v[b][c][m] = Wv[256x512] * kvr[b][m][512]^T + bv ----------------
__global__ __launch_bounds__(256) void k_proj_v(const bf16* __restrict__ W,     // [256][512]
                                                const float* __restrict__ bias, // [256]
                                                const bf16* __restrict__ Bm,    // [B][N][512]
                                                bf16* __restrict__ vout) {      // [B][256][N]
    const int mb = blockIdx.x * 64;
    const int b  = blockIdx.y;
    const int tid = threadIdx.x;
    const int w = tid >> 6, lane = tid & 63;
    const int l16 = lane & 15, quad = lane >> 4;
    f32x4 acc[4][4];
    for (int i = 0; i < 4; ++i) for (int j = 0; j < 4; ++j) acc[i][j] = (f32x4){0.f, 0.f, 0.f, 0.f};
    const bf16* bbase = Bm + ((size_t)b * N_ + mb) * CKV_ + quad * 8;
#pragma unroll 4
    for (int ks = 0; ks < 16; ++ks) {
        bf16x8 bfv[4];
        for (int j = 0; j < 4; ++j)
            bfv[j] = *(const bf16x8*)(bbase + (size_t)(j * 16 + l16) * CKV_ + ks * 32);
        for (int i = 0; i < 4; ++i) {
            bf16x8 af = *(const bf16x8*)(W + (size_t)((w * 4 + i) * 16 + l16) * CKV_ + ks * 32 + quad * 8);
            for (int j = 0; j < 4; ++j)
                acc[i][j] = __builtin_amdgcn_mfma_f32_16x16x32_bf16(af, bfv[j], acc[i][j], 0, 0, 0);
        }
    }
    for (int i = 0; i < 4; ++i)
        for (int r = 0; r < 4; ++r) {
            int c = (w * 4 + i) * 16 + quad * 4 + r;
            float bvs = bias[c];
            for (int j = 0; j < 4; ++j) {
                int m = mb + j * 16 + l16;
                vout[((size_t)b * CQ_ + c) * N_ + m] = (bf16)(acc[i][j][r] + bvs);
            }
        }
}

// ---------------- flash attention, no-max softmax, 8 waves/block ----------------
// S^T = K Q^T (operand-swapped MFMA) puts n in the lane dim and m across regs:
// each lane's 4 P values are m-contiguous -> single ds_write_b64. 8 waves
// halve per-wave chain length; 512 blocks x 512 thr = 16 waves/CU.
__global__ __launch_bounds__(512, 4) void k_flash(const bf16* __restrict__ qT,   // [B][N][32]
                                                  const bf16* __restrict__ kT,   // [B][N][32]
                                                  const bf16* __restrict__ vv,   // [B][256][N]
                                                  const float* __restrict__ query,
                                                  const float* __restrict__ gamma,
                                                  float* __restrict__ out) {
    __shared__ bf16 P[2][64][72];   // [n][m], row 144B
    __shared__ float lred[2][4][16];
    const int b  = blockIdx.y;
    const int n0 = blockIdx.x * 64;
    const int tid = threadIdx.x;
    const int w = tid >> 6;              // 0..7
    const int lane = tid & 63, l16 = lane & 15, quad = lane >> 4;
    const int jn   = w & 3;              // QK n-tile (0..3)
    const int half = w >> 2;             // QK m-half (0/1)
    const int cb   = (w & 3) * 64;       // PV c-base
    const int nh   = half;               // PV n-pair: tiles {2nh, 2nh+1}

    // Q fragment (B-operand): n = n0 + jn*16 + l16, d = quad*8..+7
    bf16x8 qfrag = *(const bf16x8*)(qT + ((size_t)b * N_ + n0 + jn * 16 + l16) * DQK_ + quad * 8);

    f32x4 acc[4][2]; // [c-tile][n-tile], c = cb + i*16 + quad*4+r, n = n0 + (2nh+j)*16 + l16
    for (int i = 0; i < 4; ++i) for (int j = 0; j < 2; ++j) acc[i][j] = (f32x4){0.f, 0.f, 0.f, 0.f};
    float lsum = 0.f; // partial row-sum for n = n0 + jn*16 + l16

    const bf16* kbase = kT + (size_t)b * N_ * DQK_;
    const bf16* vbase = vv + ((size_t)b * CQ_ + cb) * N_;

    for (int mt = 0; mt < 64; ++mt) {
        const int m0 = mt * 64;
        // prefetch V fragments (A-operand: c = cb + i*16 + l16, k = m)
        bf16x8 vf[2][4];
        for (int ks = 0; ks < 2; ++ks)
            for (int i = 0; i < 4; ++i)
                vf[ks][i] = *(const bf16x8*)(vbase + (size_t)(i * 16 + l16) * N_ + m0 + ks * 32 + quad * 8);
        // S^T = K Q^T; exp in regs; packed b64 P write
        bf16 (* __restrict__ Pb)[72] = P[mt & 1];
        for (int ii = 0; ii < 2; ++ii) {
            const int im = half * 2 + ii;
            bf16x8 kf = *(const bf16x8*)(kbase + (size_t)(m0 + im * 16 + l16) * DQK_ + quad * 8);
            f32x4 s = __builtin_amdgcn_mfma_f32_16x16x32_bf16(kf, qfrag, (f32x4){0.f, 0.f, 0.f, 0.f}, 0, 0, 0);
            bf16x4 pk;
            for (int r = 0; r < 4; ++r) {
                float p = __expf(s[r]);
                lsum += p;
                pk[r] = (bf16)p;
            }
            *(bf16x4*)&Pb[jn * 16 + l16][im * 16 + quad * 4] = pk;
        }
        __syncthreads();
        // O += V P^T
        for (int ks = 0; ks < 2; ++ks) {
            bf16x8 pf[2];
            for (int j = 0; j < 2; ++j)
                pf[j] = *(const bf16x8*)&Pb[(nh * 2 + j) * 16 + l16][ks * 32 + quad * 8];
            for (int i = 0; i < 4; ++i)
                for (int j = 0; j < 2; ++j)
                    acc[i][j] = __builtin_amdgcn_mfma_f32_16x16x32_bf16(vf[ks][i], pf[j], acc[i][j], 0, 0, 0);
        }
    }
    // row-sum: reduce across quads (all 16 values/lane belong to one row)
    lsum += __shfl_xor(lsum, 16);
    lsum += __shfl_xor(lsum, 32);
    if (lane < 16) lred[half][jn][l16] = lsum;
    __syncthreads();
    const float g = gamma[0];
    float linv[2];
    for (int j = 0; j < 2; ++j)
        linv[j] = 1.f / (lred[0][nh * 2 + j][l16] + lred[1][nh * 2 + j][l16]);
    for (int i = 0; i < 4; ++i)
        for (int r = 0; r < 4; ++r) {
            int c = cb + i * 16 + quad * 4 + r;
            for (int j = 0; j < 2; ++j) {
                int n = n0 + (nh * 2 + j) * 16 + l16;
                size_t idx = ((size_t)b * CQ_ + c) * N_ + n;
                out[idx] = g * acc[i][j][r] * linv[j] + query[idx];
            }
        }
}

extern "C" void kernel_launch(void* const* d_in, const int* in_sizes, int n_in,
                              void* d_out, int out_size, void* d_ws, size_t ws_size,
                              hipStream_t stream) {
    const float* query     = (const float*)d_in[0];
    const float* key_value = (const float*)d_in[1];
    const float* Wq = (const float*)d_in[2];
    const float* bq = (const float*)d_in[3];
    const float* Wk = (const float*)d_in[4];
    const float* bk = (const float*)d_in[5];
    const float* Wv = (const float*)d_in[6];
    const float* bv = (const float*)d_in[7];
    const float* gamma = (const float*)d_in[8];
    float* out = (float*)d_out;

    char* ws = (char*)d_ws;
    bf16* kvr  = (bf16*)(ws);              // [8][4096][512]  33,554,432 B
    bf16* vbuf = (bf16*)(ws + 33554432);   // [8][256][4096]  16,777,216 B
    bf16* qTb  = (bf16*)(ws + 50331648);   // [8][4096][32]    2,097,152 B
    bf16* kTb  = (bf16*)(ws + 52428800);   // [8][4096][32]    2,097,152 B
    bf16* wqb  = (bf16*)(ws + 54525952);   // [32][256]           16,384 B
    bf16* wkb  = (bf16*)(ws + 54542336);   // [32][512]           32,768 B
    bf16* wvb  = (bf16*)(ws + 54575104);   // [256][512]         262,144 B

    k_convert_w<<<608, 256, 0, stream>>>(Wq, Wk, Wv, wqb, wkb, wvb);
    k_resize<<<dim3(64, 8), 256, 0, stream>>>(key_value, kvr);
    k_proj_q_fused<<<dim3(64, 8), 256, 0, stream>>>(query, wqb, bq, qTb);
    k_proj_k<<<dim3(32, 8), 256, 0, stream>>>(wkb, bk, kvr, kTb);
    k_proj_v<<<dim3(64, 8), 256, 0, stream>>>(wvb, bv, kvr, vbuf);
    k_flash<<<dim3(64, 8), 512, 0, stream>>>(qTb, kTb, vbuf, query, gamma, out);
}

// Round 5
// 345.003 us; speedup vs baseline: 1.3086x; 1.3086x over previous
//
#include <hip/hip_runtime.h>

#define B_ 8
#define CQ_ 256
#define CKV_ 512
#define N_ 4096
#define DQK_ 32

typedef __bf16 bf16;
typedef __bf16 bf16x4 __attribute__((ext_vector_type(4)));
typedef __bf16 bf16x8 __attribute__((ext_vector_type(8)));
typedef float f32x4 __attribute__((ext_vector_type(4)));

// ---------------- weight convert fp32 -> bf16 ----------------
__global__ void k_convert_w(const float* __restrict__ Wq, const float* __restrict__ Wk,
                            const float* __restrict__ Wv,
                            bf16* __restrict__ wq, bf16* __restrict__ wk, bf16* __restrict__ wv) {
    int i = blockIdx.x * 256 + threadIdx.x;
    if (i < 8192) wq[i] = (bf16)Wq[i];
    else if (i < 24576) wk[i - 8192] = (bf16)Wk[i - 8192];
    else if (i < 155648) wv[i - 24576] = (bf16)Wv[i - 24576];
}

// ---------------- bilinear resize 32x32 -> 64x64, transposed to [b][n][u] ----------------
__global__ __launch_bounds__(256) void k_resize(const float* __restrict__ kv, bf16* __restrict__ kvr) {
    const int yo = blockIdx.x;   // output row 0..63
    const int b  = blockIdx.y;
    const int tid = threadIdx.x;
    __shared__ float r0[64][33];
    __shared__ float r1[64][33];
    int ty = yo >> 1;
    int y0, y1; float wy0, wy1;
    if ((yo & 1) == 0) { y0 = ty > 0 ? ty - 1 : 0; y1 = ty; wy0 = 0.25f; wy1 = 0.75f; }
    else               { y0 = ty; y1 = ty < 31 ? ty + 1 : 31; wy0 = 0.75f; wy1 = 0.25f; }
    const int u_loc = tid & 63;
    const int xo_base = tid >> 6;
    for (int uc = 0; uc < CKV_; uc += 64) {
        __syncthreads();
        for (int i = 0; i < 8; ++i) {
            int idx = tid + i * 256;
            int u = idx >> 5, x = idx & 31;
            const float* src = kv + ((size_t)b * CKV_ + uc + u) * 1024 + x;
            r0[u][x] = src[y0 * 32];
            r1[u][x] = src[y1 * 32];
        }
        __syncthreads();
        for (int i = 0; i < 16; ++i) {
            int xo = xo_base + i * 4;
            int tx = xo >> 1;
            int xa, xb; float wxa, wxb;
            if ((xo & 1) == 0) { xa = tx > 0 ? tx - 1 : 0; xb = tx; wxa = 0.25f; wxb = 0.75f; }
            else               { xa = tx; xb = tx < 31 ? tx + 1 : 31; wxa = 0.75f; wxb = 0.25f; }
            float v0 = wxa * r0[u_loc][xa] + wxb * r0[u_loc][xb];
            float v1 = wxa * r1[u_loc][xa] + wxb * r1[u_loc][xb];
            float val = wy0 * v0 + wy1 * v1;
            kvr[((size_t)b * N_ + yo * 64 + xo) * CKV_ + uc + u_loc] = (bf16)val;
        }
    }
}

// ---------------- fused: transpose query tile to LDS + q projection ----------------
__global__ __launch_bounds__(256) void k_proj_q_fused(const float* __restrict__ query,
                                                      const bf16* __restrict__ W,     // [32][256]
                                                      const float* __restrict__ bias, // [32]
                                                      bf16* __restrict__ qTb) {       // [B][N][32]
    __shared__ bf16 tile[64][264];   // [n][c], row stride 528B (16B-aligned)
    const int n0 = blockIdx.x * 64;
    const int b  = blockIdx.y;
    const int tid = threadIdx.x;
    const int xi = tid & 15, c0 = tid >> 4;
    for (int pass = 0; pass < 16; ++pass) {
        int c = c0 + pass * 16;
        const float4 v = *(const float4*)(query + ((size_t)b * CQ_ + c) * N_ + n0 + xi * 4);
        tile[xi * 4 + 0][c] = (bf16)v.x;
        tile[xi * 4 + 1][c] = (bf16)v.y;
        tile[xi * 4 + 2][c] = (bf16)v.z;
        tile[xi * 4 + 3][c] = (bf16)v.w;
    }
    __syncthreads();
    const int w = tid >> 6, lane = tid & 63;
    const int l16 = lane & 15, quad = lane >> 4;
    const int ct = w & 1, nh = w >> 1;
    f32x4 acc[2];
    acc[0] = (f32x4){0.f, 0.f, 0.f, 0.f}; acc[1] = (f32x4){0.f, 0.f, 0.f, 0.f};
    const bf16* aptr = W + (ct * 16 + l16) * CQ_ + quad * 8;
#pragma unroll
    for (int ks = 0; ks < 8; ++ks) {
        bf16x8 af = *(const bf16x8*)(aptr + ks * 32);
        for (int j = 0; j < 2; ++j) {
            bf16x8 bfv = *(const bf16x8*)&tile[nh * 32 + j * 16 + l16][ks * 32 + quad * 8];
            acc[j] = __builtin_amdgcn_mfma_f32_16x16x32_bf16(af, bfv, acc[j], 0, 0, 0);
        }
    }
    for (int j = 0; j < 2; ++j)
        for (int r = 0; r < 4; ++r) {
            int d = ct * 16 + quad * 4 + r;
            int n = n0 + nh * 32 + j * 16 + l16;
            qTb[((size_t)b * N_ + n) * DQK_ + d] = (bf16)(acc[j][r] + bias[d]);
        }
}

// ---------------- k projection ----------------
__global__ __launch_bounds__(256) void k_proj_k(const bf16* __restrict__ W,     // [32][512]
                                                const float* __restrict__ bias, // [32]
                                                const bf16* __restrict__ Bm,    // [B][N][512]
                                                bf16* __restrict__ outT) {      // [B][N][32]
    const int mb = blockIdx.x * 128;
    const int b  = blockIdx.y;
    const int tid = threadIdx.x;
    const int w = tid >> 6, lane = tid & 63;
    const int l16 = lane & 15, quad = lane >> 4;
    const int ct = w & 1;
    const int mhalf = (w >> 1) * 64;
    f32x4 acc[4];
    for (int j = 0; j < 4; ++j) acc[j] = (f32x4){0.f, 0.f, 0.f, 0.f};
    const bf16* aptr  = W + (ct * 16 + l16) * CKV_ + quad * 8;
    const bf16* bbase = Bm + ((size_t)b * N_ + mb + mhalf) * CKV_ + quad * 8;
#pragma unroll
    for (int ks = 0; ks < 16; ++ks) {
        bf16x8 af = *(const bf16x8*)(aptr + ks * 32);
        for (int j = 0; j < 4; ++j) {
            bf16x8 bfv = *(const bf16x8*)(bbase + (size_t)(j * 16 + l16) * CKV_ + ks * 32);
            acc[j] = __builtin_amdgcn_mfma_f32_16x16x32_bf16(af, bfv, acc[j], 0, 0, 0);
        }
    }
    for (int j = 0; j < 4; ++j)
        for (int r = 0; r < 4; ++r) {
            int d = ct * 16 + quad * 4 + r;
            int m = mb + mhalf + j * 16 + l16;
            outT[((size_t)b * N_ + m) * DQK_ + d] = (bf16)(acc[j][r] + bias[d]);
        }
}

// ---------------- v projection ----------------
__global__ __launch_bounds__(256) void k_proj_v(const bf16* __restrict__ W,     // [256][512]
                                                const float* __restrict__ bias, // [256]
                                                const bf16* __restrict__ Bm,    // [B][N][512]
                                                bf16* __restrict__ vout) {      // [B][256][N]
    const int mb = blockIdx.x * 64;
    const int b  = blockIdx.y;
    const int tid = threadIdx.x;
    const int w = tid >> 6, lane = tid & 63;
    const int l16 = lane & 15, quad = lane >> 4;
    f32x4 acc[4][4];
    for (int i = 0; i < 4; ++i) for (int j = 0; j < 4; ++j) acc[i][j] = (f32x4){0.f, 0.f, 0.f, 0.f};
    const bf16* bbase = Bm + ((size_t)b * N_ + mb) * CKV_ + quad * 8;
#pragma unroll 4
    for (int ks = 0; ks < 16; ++ks) {
        bf16x8 bfv[4];
        for (int j = 0; j < 4; ++j)
            bfv[j] = *(const bf16x8*)(bbase + (size_t)(j * 16 + l16) * CKV_ + ks * 32);
        for (int i = 0; i < 4; ++i) {
            bf16x8 af = *(const bf16x8*)(W + (size_t)((w * 4 + i) * 16 + l16) * CKV_ + ks * 32 + quad * 8);
            for (int j = 0; j < 4; ++j)
                acc[i][j] = __builtin_amdgcn_mfma_f32_16x16x32_bf16(af, bfv[j], acc[i][j], 0, 0, 0);
        }
    }
    for (int i = 0; i < 4; ++i)
        for (int r = 0; r < 4; ++r) {
            int c = (w * 4 + i) * 16 + quad * 4 + r;
            float bvs = bias[c];
            for (int j = 0; j < 4; ++j) {
                int m = mb + j * 16 + l16;
                vout[((size_t)b * CQ_ + c) * N_ + m] = (bf16)(acc[i][j][r] + bvs);
            }
        }
}

// ---------------- flash attention: BARRIER-FREE, wave-private P ----------------
// Each wave redundantly computes the full 64x64 S^T tile (operand-swapped
// K*Q^T MFMAs), exps in registers, round-trips P through its OWN LDS region
// (DS ops are in-order per wave -> no __syncthreads anywhere), then computes
// its 64-channel slice of O += V P^T. Waves fully decoupled; softmax denom
// lives in registers (quad shfl-reduce at the end). P chunks XOR-swizzled by
// (l16&3) to kill the 4-way b64 write conflicts.
__global__ __launch_bounds__(256) void k_flash(const bf16* __restrict__ qT,   // [B][N][32]
                                               const bf16* __restrict__ kT,   // [B][N][32]
                                               const bf16* __restrict__ vv,   // [B][256][N]
                                               const float* __restrict__ query,
                                               const float* __restrict__ gamma,
                                               float* __restrict__ out) {
    __shared__ bf16 P[4][64][72];   // [wave][n][m-chunk swizzled]; 36,864 B
    const int b  = blockIdx.y;
    const int n0 = blockIdx.x * 64;
    const int tid = threadIdx.x;
    const int w = tid >> 6, lane = tid & 63;
    const int l16 = lane & 15, quad = lane >> 4;
    const int swz = l16 & 3;

    // Q fragments (B-operand), loop-invariant: n = n0 + jn*16 + l16, d = quad*8..+7
    bf16x8 qfrag[4];
    for (int jn = 0; jn < 4; ++jn)
        qfrag[jn] = *(const bf16x8*)(qT + ((size_t)b * N_ + n0 + jn * 16 + l16) * DQK_ + quad * 8);

    f32x4 acc[4][4];   // [c-tile i][n-tile j]: c = w*64+i*16+quad*4+r, n = n0+j*16+l16
    for (int i = 0; i < 4; ++i) for (int j = 0; j < 4; ++j) acc[i][j] = (f32x4){0.f, 0.f, 0.f, 0.f};
    f32x4 lsum4[4];    // per n-tile partial softmax denom (4 indep chains each)
    for (int j = 0; j < 4; ++j) lsum4[j] = (f32x4){0.f, 0.f, 0.f, 0.f};

    const bf16* kbase = kT + (size_t)b * N_ * DQK_;
    const bf16* vbase = vv + ((size_t)b * CQ_ + w * 64) * N_;
    bf16 (* __restrict__ Pw)[72] = P[w];

    for (int mt = 0; mt < 64; ++mt) {
        const int m0 = mt * 64;
        // K fragments (A-operand): m = m0 + im*16 + l16, d = quad*8..+7
        bf16x8 kf[4];
        for (int im = 0; im < 4; ++im)
            kf[im] = *(const bf16x8*)(kbase + (size_t)(m0 + im * 16 + l16) * DQK_ + quad * 8);
        // V fragments (A-operand): c = w*64 + i*16 + l16, k = m
        bf16x8 vf[2][4];
        for (int ks = 0; ks < 2; ++ks)
            for (int i = 0; i < 4; ++i)
                vf[ks][i] = *(const bf16x8*)(vbase + (size_t)(i * 16 + l16) * N_ + m0 + ks * 32 + quad * 8);
        // S^T = K Q^T (full 64x64, this wave alone); exp; wave-private P write.
        // D: col(l16)=n, row(quad*4+r)=m_local -> lane's 4 values m-contiguous.
        for (int jn = 0; jn < 4; ++jn) {
            for (int im = 0; im < 4; ++im) {
                f32x4 s = __builtin_amdgcn_mfma_f32_16x16x32_bf16(kf[im], qfrag[jn],
                                                                  (f32x4){0.f, 0.f, 0.f, 0.f}, 0, 0, 0);
                bf16x4 pk;
                for (int r = 0; r < 4; ++r) {
                    float p = __expf(s[r]);
                    lsum4[jn][r] += p;
                    pk[r] = (bf16)p;
                }
                *(bf16x4*)&Pw[jn * 16 + l16][((im ^ swz) << 4) + quad * 4] = pk;
            }
        }
        // O += V P^T (reads only this wave's P; in-order DS => no barrier)
        for (int ks = 0; ks < 2; ++ks) {
            bf16x8 pf[4];
            for (int j = 0; j < 4; ++j)
                pf[j] = *(const bf16x8*)&Pw[j * 16 + l16]
                            [((((ks << 1) | (quad >> 1)) ^ swz) << 4) + ((quad & 1) << 3)];
            for (int i = 0; i < 4; ++i)
                for (int j = 0; j < 4; ++j)
                    acc[i][j] = __builtin_amdgcn_mfma_f32_16x16x32_bf16(vf[ks][i], pf[j], acc[i][j], 0, 0, 0);
        }
    }
    // softmax denominators: horizontal sum + reduce across quads (lanes l16+16k share n)
    float linv[4];
    for (int j = 0; j < 4; ++j) {
        float s = (lsum4[j][0] + lsum4[j][1]) + (lsum4[j][2] + lsum4[j][3]);
        s += __shfl_xor(s, 16);
        s += __shfl_xor(s, 32);
        linv[j] = 1.f / s;
    }
    const float g = gamma[0];
    for (int i = 0; i < 4; ++i)
        for (int r = 0; r < 4; ++r) {
            int c = w * 64 + i * 16 + quad * 4 + r;
            for (int j = 0; j < 4; ++j) {
                int n = n0 + j * 16 + l16;
                size_t idx = ((size_t)b * CQ_ + c) * N_ + n;
                out[idx] = g * acc[i][j][r] * linv[j] + query[idx];
            }
        }
}

extern "C" void kernel_launch(void* const* d_in, const int* in_sizes, int n_in,
                              void* d_out, int out_size, void* d_ws, size_t ws_size,
                              hipStream_t stream) {
    const float* query     = (const float*)d_in[0];
    const float* key_value = (const float*)d_in[1];
    const float* Wq = (const float*)d_in[2];
    const float* bq = (const float*)d_in[3];
    const float* Wk = (const float*)d_in[4];
    const float* bk = (const float*)d_in[5];
    const float* Wv = (const float*)d_in[6];
    const float* bv = (const float*)d_in[7];
    const float* gamma = (const float*)d_in[8];
    float* out = (float*)d_out;

    char* ws = (char*)d_ws;
    bf16* kvr  = (bf16*)(ws);              // [8][4096][512]  33,554,432 B
    bf16* vbuf = (bf16*)(ws + 33554432);   // [8][256][4096]  16,777,216 B
    bf16* qTb  = (bf16*)(ws + 50331648);   // [8][4096][32]    2,097,152 B
    bf16* kTb  = (bf16*)(ws + 52428800);   // [8][4096][32]    2,097,152 B
    bf16* wqb  = (bf16*)(ws + 54525952);   // [32][256]           16,384 B
    bf16* wkb  = (bf16*)(ws + 54542336);   // [32][512]           32,768 B
    bf16* wvb  = (bf16*)(ws + 54575104);   // [256][512]         262,144 B

    k_convert_w<<<608, 256, 0, stream>>>(Wq, Wk, Wv, wqb, wkb, wvb);
    k_resize<<<dim3(64, 8), 256, 0, stream>>>(key_value, kvr);
    k_proj_q_fused<<<dim3(64, 8), 256, 0, stream>>>(query, wqb, bq, qTb);
    k_proj_k<<<dim3(32, 8), 256, 0, stream>>>(wkb, bk, kvr, kTb);
    k_proj_v<<<dim3(64, 8), 256, 0, stream>>>(wvb, bv, kvr, vbuf);
    k_flash<<<dim3(64, 8), 256, 0, stream>>>(qTb, kTb, vbuf, query, gamma, out);
}